// Round 10
// baseline (208.812 us; speedup 1.0000x reference)
//
#include <hip/hip_runtime.h>
#include <cstdint>

typedef _Float16 f16;
typedef _Float16 f16x4 __attribute__((ext_vector_type(4)));
typedef _Float16 f16x8 __attribute__((ext_vector_type(8)));
typedef float f32x4 __attribute__((ext_vector_type(4)));

#define MFMA16(a, b, c) __builtin_amdgcn_mfma_f32_16x16x32_f16(a, b, c, 0, 0, 0)
#define QSCALE 0.1803368801111243f  /* 0.125 * log2(e): scores land in log2 domain */

// direct global->LDS 16B async copy (m97 pattern)
__device__ __forceinline__ void gload_lds16(const void* g, void* l) {
    __builtin_amdgcn_global_load_lds((__attribute__((address_space(1))) void*)(g),
                                     (__attribute__((address_space(3))) void*)(l),
                                     16, 0, 0);
}

// Problem constants: S=2048, B=2, D=1024, H=16, DK=64
// ws layout (bytes):
//  xh   @ 0         : 4096x1024 f16 = 8 MB       (dead after gemm_qkv)
//  wqh  @ 8388608   : 3072x1024 f16 = 6 MB
//  woh  @ 14680064  : 1024x1024 f16 = 2 MB
//  qh   @ 16777216  : [32][2048][64] f16 = 8 MB  (PRE-SCALED by 0.125*log2e)
//  kh   @ 25165824  : [32][2048][64] f16 = 8 MB
//  vt   @ 33554432  : [32][64][2048] f16 = 8 MB  (V transposed, written by gemm_qkv)
//  ah   @ 41943040  : [4096][1024] f16 = 8 MB

// Single fused cast: outputs are contiguous in ws (xh | wqh | woh).
__global__ void cast_all(const float* __restrict__ x, const float* __restrict__ wqv,
                         const float* __restrict__ wo, f16* __restrict__ out) {
    int i = blockIdx.x * blockDim.x + threadIdx.x;  // 0..2097151 float4s
    const float* src; int li;
    if (i < 1048576)      { src = x;   li = i; }
    else if (i < 1835008) { src = wqv; li = i - 1048576; }
    else                  { src = wo;  li = i - 1835008; }
    float4 v = reinterpret_cast<const float4*>(src)[li];
    f16x4 o = {(f16)v.x, (f16)v.y, (f16)v.z, (f16)v.w};
    reinterpret_cast<f16x4*>(out)[i] = o;
}

// ---------------- QKV GEMM: C[4096x3072] = X[4096x1024] * Wqkv^T ----------------
// R7: 3-deep pipelined K-loop. BK=32, 3 LDS buffers (ring t%3): while computing
// tile t, tile t+2 is being staged; tile t+1 is landing. One raw s_barrier per
// tile with counted s_waitcnt vmcnt(4) (never drains the queue in steady state).
__global__ __launch_bounds__(256, 3) void gemm_qkv(
    const f16* __restrict__ A, const f16* __restrict__ B,
    f16* __restrict__ outq, f16* __restrict__ outk, f16* __restrict__ outvt)
{
    __shared__ f16 As[3][128 * 32];
    __shared__ f16 Bs[3][128 * 32];
    const int tid = threadIdx.x;
    const int lane = tid & 63;
    const int wave = tid >> 6;
    const int wm = wave >> 1, wn = wave & 1;
    const int bm = blockIdx.y * 128, bn = blockIdx.x * 128;
    const int fr = lane & 15, fq = lane >> 4;

    const int srow = tid >> 2;                                    // 0..63
    const int su = (tid & 3) ^ (srow & 3) ^ ((srow >> 2) & 3);    // swizzled src 16B-unit
    const int uoff = (fq ^ (fr & 3) ^ ((fr >> 2) & 3)) * 8;       // lane-const read offset

    f32x4 acc[4][4] = {};

    auto stg = [&](int tt, int buf) {
        const int k0 = tt * 32;
        gload_lds16(&A[(bm + srow) * 1024 + k0 + su * 8],      &As[buf][tid * 8]);
        gload_lds16(&A[(bm + 64 + srow) * 1024 + k0 + su * 8], &As[buf][2048 + tid * 8]);
        gload_lds16(&B[(bn + srow) * 1024 + k0 + su * 8],      &Bs[buf][tid * 8]);
        gload_lds16(&B[(bn + 64 + srow) * 1024 + k0 + su * 8], &Bs[buf][2048 + tid * 8]);
    };

    auto step = [&](int t, int buf) {
        const int b2 = (buf + 2 >= 3) ? (buf - 1) : (buf + 2);
        if (t < 30) stg(t + 2, b2);
        f16x8 af[4], bf[4];
#pragma unroll
        for (int mt = 0; mt < 4; ++mt)
            af[mt] = *(const f16x8*)&As[buf][(wm * 64 + mt * 16 + fr) * 32 + uoff];
#pragma unroll
        for (int nt = 0; nt < 4; ++nt)
            bf[nt] = *(const f16x8*)&Bs[buf][(wn * 64 + nt * 16 + fr) * 32 + uoff];
        __builtin_amdgcn_s_setprio(1);
#pragma unroll
        for (int mt = 0; mt < 4; ++mt)
#pragma unroll
            for (int nt = 0; nt < 4; ++nt)
                acc[mt][nt] = MFMA16(af[mt], bf[nt], acc[mt][nt]);
        __builtin_amdgcn_s_setprio(0);
        if (t < 30) { asm volatile("s_waitcnt vmcnt(4)" ::: "memory"); }
        else        { asm volatile("s_waitcnt vmcnt(0)" ::: "memory"); }
        __builtin_amdgcn_s_barrier();
        __builtin_amdgcn_sched_barrier(0);
    };

    stg(0, 0);
    stg(1, 1);
    asm volatile("s_waitcnt vmcnt(4)" ::: "memory");
    __builtin_amdgcn_s_barrier();
    __builtin_amdgcn_sched_barrier(0);
#pragma unroll 1
    for (int tb = 0; tb < 30; tb += 3) {
        step(tb, 0);
        step(tb + 1, 1);
        step(tb + 2, 2);
    }
    step(30, 0);
    step(31, 1);

    const int x = blockIdx.x;
    if (x < 16) {
        // Q (x<8) or K block: uniform target, row-layout [bh][s][64]
        f16* base = (x < 8) ? outq : outk;
        const float scale = (x < 8) ? QSCALE : 1.0f;
        const int coloff = (x < 8) ? bn : (bn - 1024);
#pragma unroll
        for (int mt = 0; mt < 4; ++mt)
#pragma unroll
            for (int nt = 0; nt < 4; ++nt)
#pragma unroll
                for (int i = 0; i < 4; ++i) {
                    int row = bm + wm * 64 + mt * 16 + fq * 4 + i;  // (s*2+b)
                    int col = coloff + wn * 64 + nt * 16 + fr;      // 0..1023
                    int s = row >> 1, b = row & 1;
                    int h = col >> 6, dk = col & 63;
                    base[((b * 16 + h) * 2048 + s) * 64 + dk] = (f16)(acc[mt][nt][i] * scale);
                }
    } else {
        // V block: LDS transpose (2 passes over wn halves) -> vt[bh][dk][s]
        const int xb = x - 16;              // 0..7
        const int s0 = bm >> 1;             // 64-aligned s base
        f16* Ts = &As[0][0];                // [128][76] = 9728 f16 (fits in As[3][4096])
#pragma unroll
        for (int p = 0; p < 2; ++p) {
            __syncthreads();
            if (wn == p) {
#pragma unroll
                for (int mt = 0; mt < 4; ++mt)
#pragma unroll
                    for (int nt = 0; nt < 4; ++nt)
#pragma unroll
                        for (int i = 0; i < 4; ++i) {
                            int row = wm * 64 + mt * 16 + fq * 4 + i;  // 0..127 local
                            int cl = nt * 16 + fr;                     // 0..63 local col
                            Ts[(cl * 2 + (row & 1)) * 76 + (row >> 1)] = (f16)acc[mt][nt][i];
                        }
            }
            __syncthreads();
            const int h = xb * 2 + p;
            const int sj = tid & 7;
#pragma unroll
            for (int it = 0; it < 4; ++it) {
                int idx = (tid >> 3) + it * 32;     // 0..127
                int bsel = idx & 1, dk = idx >> 1;  // b, dk(=cl)
                f16x8 v = *(const f16x8*)&Ts[(dk * 2 + bsel) * 76 + sj * 8];
                *(f16x8*)&outvt[((bsel * 16 + h) * 64 + dk) * 2048 + s0 + sj * 8] = v;
            }
        }
    }
}

// ---------------- Flash attention (causal) — R15: R11 + V direct-from-L2 ----------------
// REVERT to R11 (best measured 42.2us: 8 waves, complementary A/B tile split,
// LDS-P round-trip, XCD swizzle bh%8==XCD, K ring-3 + counted vmcnt, setprio).
// R13/R14 falsified tile-restructure: per-iteration cost is latency-dominated and
// co-resident waves hide it; keep the R11 iteration structure.
// NEW (m169 precedent: drop LDS staging for L2-fit data): V is NOT staged in LDS.
// Each wave loads its 8 PV B-frags directly from global VT (L2-resident, 2MB/XCD;
// plain layout: bv0 = VT[dk][kb+fq*8], bv1 = +32 — the LDS XOR-swizzle cancels).
// Loads issue at iteration top; QK+SM (~400cyc) covers L2 latency (~200cyc); the
// compiler inserts exact counted waits for these REGISTER loads, so the K prefetch
// stays in flight. Barrier invariant: only the newest K stage outstanding ->
// vmcnt(1)/(0), valid for all waves (A-waves issue no V loads). LDS 67.6->42.4KB.
__global__ __launch_bounds__(512) void attn_kernel(
    const f16* __restrict__ qg, const f16* __restrict__ kg,
    const f16* __restrict__ vtg, f16* __restrict__ attn)
{
    __shared__ f16 Ks[3][64 * 64];
    __shared__ f16 plds[8][16 * 72];
    const int tid = threadIdx.x;
    const int lane = tid & 63;
    const int wave = tid >> 6;      // 0..7

    // XCD-aware remap (bijective on 512): XCD = w&7 == bh&7
    const int w = blockIdx.x + (blockIdx.y << 4);
    const int xcd = w & 7;
    const int idx = w >> 3;                  // 0..63 within XCD, dispatch order
    const int bh = xcd + ((idx & 3) << 3);   // 0..31, bh%8 == xcd
    const int qpair = idx >> 2;              // 0..15, longest stream first

    const int b = bh >> 4, h = bh & 15;
    const int fr = lane & 15, fq = lane >> 4;

    const bool isB = wave < 4;
    const int w4 = wave & 3;
    const int qrow = (isB ? (31 - qpair) : qpair) * 64 + w4 * 16;  // wave's 16-row base
    const int nB = 32 - qpair;              // chunks streamed by the block (>=17)
    const int nK = isB ? nB : (qpair + 1);  // chunks this wave computes

    const f16* Q  = qg  + bh * 2048 * 64;
    const f16* K  = kg  + bh * 2048 * 64;
    const f16* VT = vtg + bh * 64 * 2048;
    f16* P = plds[wave];

    const int sr = tid >> 3;                // 0..63: full 64-row chunk in one issue
    const int scu = (tid & 7) ^ (sr & 7);

    f16x8 aq0 = *(const f16x8*)&Q[(qrow + fr) * 64 + fq * 8];
    f16x8 aq1 = *(const f16x8*)&Q[(qrow + fr) * 64 + 32 + fq * 8];

    f32x4 o[4] = {};
    float l[4] = {};
    f16x8 vf0[4], vf1[4];                   // V frags, loaded from L2 each chunk

    auto stage = [&](int kc, int buf) {
        gload_lds16(&K[(kc * 64 + sr) * 64 + scu * 8], &Ks[buf][tid * 8]);
    };

    auto compute = [&](int kb, const f16* Ksb, bool domask) {
        f32x4 sc[4] = {};
        __builtin_amdgcn_s_setprio(1);
#pragma unroll
        for (int ct = 0; ct < 4; ++ct) {
            int r = ct * 16 + fr;
            f16x8 b0 = *(const f16x8*)&Ksb[r * 64 + ((fq ^ (r & 7)) * 8)];
            f16x8 b1 = *(const f16x8*)&Ksb[r * 64 + (((4 + fq) ^ (r & 7)) * 8)];
            sc[ct] = MFMA16(aq0, b0, sc[ct]);
            sc[ct] = MFMA16(aq1, b1, sc[ct]);
        }
        __builtin_amdgcn_s_setprio(0);
        if (domask) {
#pragma unroll
            for (int ct = 0; ct < 4; ++ct) {
                int kcol = kb + ct * 16 + fr;
#pragma unroll
                for (int i = 0; i < 4; ++i)
                    if (kcol > qrow + fq * 4 + i) sc[ct][i] = -1e30f;
            }
        }
#pragma unroll
        for (int i = 0; i < 4; ++i) {
            float p0 = __builtin_amdgcn_exp2f(sc[0][i]);
            float p1 = __builtin_amdgcn_exp2f(sc[1][i]);
            float p2 = __builtin_amdgcn_exp2f(sc[2][i]);
            float p3 = __builtin_amdgcn_exp2f(sc[3][i]);
            l[i] += (p0 + p1) + (p2 + p3);
            P[(fq * 4 + i) * 72 + fr]      = (f16)p0;
            P[(fq * 4 + i) * 72 + 16 + fr] = (f16)p1;
            P[(fq * 4 + i) * 72 + 32 + fr] = (f16)p2;
            P[(fq * 4 + i) * 72 + 48 + fr] = (f16)p3;
        }
        f16x8 ap0 = *(const f16x8*)&P[fr * 72 + fq * 8];
        f16x8 ap1 = *(const f16x8*)&P[fr * 72 + 32 + fq * 8];
        __builtin_amdgcn_s_setprio(1);
#pragma unroll
        for (int nt = 0; nt < 4; ++nt) {
            o[nt] = MFMA16(ap0, vf0[nt], o[nt]);
            o[nt] = MFMA16(ap1, vf1[nt], o[nt]);
        }
        __builtin_amdgcn_s_setprio(0);
    };

    // prologue: stage K 0,1; wait for 0 (1 may stay in flight across the barrier)
    stage(0, 0);
    stage(1, 1);
    asm volatile("s_waitcnt vmcnt(1)" ::: "memory");
    __builtin_amdgcn_s_barrier();
    __builtin_amdgcn_sched_barrier(0);

    int cur = 0;
#pragma unroll 1
    for (int kc = 0; kc < nB; ++kc) {
        const int kb = kc * 64;
        if (kc < nK) {
            // V frags for THIS chunk, direct from global (L2). Issued before QK so
            // the QK+SM phase covers the L2 latency; compiler auto-waits before PV.
#pragma unroll
            for (int nt = 0; nt < 4; ++nt) {
                const f16* vrow = VT + (nt * 16 + fr) * 2048 + kb;
                vf0[nt] = *(const f16x8*)&vrow[fq * 8];
                vf1[nt] = *(const f16x8*)&vrow[32 + fq * 8];
            }
        }
        if (kc + 2 < nB) {
            int b2 = cur + 2; if (b2 >= 3) b2 -= 3;
            stage(kc + 2, b2);
        }
        if (kc < nK) compute(kb, Ks[cur], kb + 63 > qrow);
        if (kc + 2 < nB) { asm volatile("s_waitcnt vmcnt(1)" ::: "memory"); }
        else             { asm volatile("s_waitcnt vmcnt(0)" ::: "memory"); }
        __builtin_amdgcn_s_barrier();
        __builtin_amdgcn_sched_barrier(0);
        if (++cur == 3) cur = 0;
    }

#pragma unroll
    for (int i = 0; i < 4; ++i) {
        float rs = l[i];
        rs += __shfl_xor(rs, 1);
        rs += __shfl_xor(rs, 2);
        rs += __shfl_xor(rs, 4);
        rs += __shfl_xor(rs, 8);
        float inv = __builtin_amdgcn_rcpf(rs);
        int srow = qrow + fq * 4 + i;
#pragma unroll
        for (int nt = 0; nt < 4; ++nt)
            attn[(srow * 2 + b) * 1024 + h * 64 + nt * 16 + fr] = (f16)(o[nt][i] * inv);
    }
}

// ---------------- Out GEMM: out[4096x1024] = A[4096x1024] * Wout^T + bias ----------------
// Same 3-deep pipelined structure as gemm_qkv (BK=32, ring of 3, counted vmcnt).
__global__ __launch_bounds__(256) void gemm_out(
    const f16* __restrict__ A, const f16* __restrict__ B,
    const float* __restrict__ bias, float* __restrict__ out)
{
    __shared__ f16 As[3][128 * 32];
    __shared__ f16 Bs[3][64 * 32];
    const int tid = threadIdx.x;
    const int lane = tid & 63;
    const int wave = tid >> 6;
    const int wm = wave >> 1, wn = wave & 1;
    const int bm = blockIdx.y * 128, bn = blockIdx.x * 64;
    const int fr = lane & 15, fq = lane >> 4;

    const int srow = tid >> 2;                                    // 0..63
    const int su = (tid & 3) ^ (srow & 3) ^ ((srow >> 2) & 3);
    const int uoff = (fq ^ (fr & 3) ^ ((fr >> 2) & 3)) * 8;

    f32x4 acc[4][2] = {};

    auto stg = [&](int tt, int buf) {
        const int k0 = tt * 32;
        gload_lds16(&A[(bm + srow) * 1024 + k0 + su * 8],      &As[buf][tid * 8]);
        gload_lds16(&A[(bm + 64 + srow) * 1024 + k0 + su * 8], &As[buf][2048 + tid * 8]);
        gload_lds16(&B[(bn + srow) * 1024 + k0 + su * 8],      &Bs[buf][tid * 8]);
    };

    auto step = [&](int t, int buf) {
        const int b2 = (buf + 2 >= 3) ? (buf - 1) : (buf + 2);
        if (t < 30) stg(t + 2, b2);
        f16x8 af[4], bf[2];
#pragma unroll
        for (int mt = 0; mt < 4; ++mt)
            af[mt] = *(const f16x8*)&As[buf][(wm * 64 + mt * 16 + fr) * 32 + uoff];
#pragma unroll
        for (int nt = 0; nt < 2; ++nt)
            bf[nt] = *(const f16x8*)&Bs[buf][(wn * 32 + nt * 16 + fr) * 32 + uoff];
        __builtin_amdgcn_s_setprio(1);
#pragma unroll
        for (int mt = 0; mt < 4; ++mt)
#pragma unroll
            for (int nt = 0; nt < 2; ++nt)
                acc[mt][nt] = MFMA16(af[mt], bf[nt], acc[mt][nt]);
        __builtin_amdgcn_s_setprio(0);
        if (t < 30) { asm volatile("s_waitcnt vmcnt(3)" ::: "memory"); }
        else        { asm volatile("s_waitcnt vmcnt(0)" ::: "memory"); }
        __builtin_amdgcn_s_barrier();
        __builtin_amdgcn_sched_barrier(0);
    };

    stg(0, 0);
    stg(1, 1);
    asm volatile("s_waitcnt vmcnt(3)" ::: "memory");
    __builtin_amdgcn_s_barrier();
    __builtin_amdgcn_sched_barrier(0);
#pragma unroll 1
    for (int tb = 0; tb < 30; tb += 3) {
        step(tb, 0);
        step(tb + 1, 1);
        step(tb + 2, 2);
    }
    step(30, 0);
    step(31, 1);

#pragma unroll
    for (int mt = 0; mt < 4; ++mt)
#pragma unroll
        for (int nt = 0; nt < 2; ++nt)
#pragma unroll
            for (int i = 0; i < 4; ++i) {
                int row = bm + wm * 64 + mt * 16 + fq * 4 + i;
                int col = bn + wn * 32 + nt * 16 + fr;
                out[row * 1024 + col] = acc[mt][nt][i] + bias[col];
            }
}

extern "C" void kernel_launch(void* const* d_in, const int* in_sizes, int n_in,
                              void* d_out, int out_size, void* d_ws, size_t ws_size,
                              hipStream_t stream)
{
    const float* x     = (const float*)d_in[0];
    const float* w_qkv = (const float*)d_in[1];
    const float* w_out = (const float*)d_in[2];
    const float* b_out = (const float*)d_in[3];
    float* out = (float*)d_out;

    char* ws = (char*)d_ws;
    f16* xh  = (f16*)(ws);
    f16* wqh = (f16*)(ws + 8388608);
    f16* woh = (f16*)(ws + 14680064);
    f16* qh  = (f16*)(ws + 16777216);
    f16* kh  = (f16*)(ws + 25165824);
    f16* vt  = (f16*)(ws + 33554432);
    f16* ah  = (f16*)(ws + 41943040);

    cast_all<<<8192, 256, 0, stream>>>(x, w_qkv, w_out, xh);
    gemm_qkv<<<dim3(24, 32), 256, 0, stream>>>(xh, wqh, qh, kh, vt);
    attn_kernel<<<dim3(16, 32), 512, 0, stream>>>(qh, kh, vt, ah);
    gemm_out<<<dim3(16, 32), 256, 0, stream>>>(ah, woh, b_out, out);
}

// Round 11
// 172.274 us; speedup vs baseline: 1.2121x; 1.2121x over previous
//
#include <hip/hip_runtime.h>
#include <cstdint>

typedef _Float16 f16;
typedef _Float16 f16x4 __attribute__((ext_vector_type(4)));
typedef _Float16 f16x8 __attribute__((ext_vector_type(8)));
typedef float f32x4 __attribute__((ext_vector_type(4)));

#define MFMA16(a, b, c) __builtin_amdgcn_mfma_f32_16x16x32_f16(a, b, c, 0, 0, 0)
#define QSCALE 0.1803368801111243f  /* 0.125 * log2(e): scores land in log2 domain */

// direct global->LDS 16B async copy (m97 pattern)
__device__ __forceinline__ void gload_lds16(const void* g, void* l) {
    __builtin_amdgcn_global_load_lds((__attribute__((address_space(1))) void*)(g),
                                     (__attribute__((address_space(3))) void*)(l),
                                     16, 0, 0);
}

// Problem constants: S=2048, B=2, D=1024, H=16, DK=64
// ws layout (bytes):
//  xh   @ 0         : 4096x1024 f16 = 8 MB       (dead after gemm_qkv)
//  wqh  @ 8388608   : 3072x1024 f16 = 6 MB
//  woh  @ 14680064  : 1024x1024 f16 = 2 MB
//  qh   @ 16777216  : [32][2048][64] f16 = 8 MB  (PRE-SCALED by 0.125*log2e)
//  kh   @ 25165824  : [32][2048][64] f16 = 8 MB
//  vt   @ 33554432  : [32][64][2048] f16 = 8 MB  (V transposed, written by gemm_qkv)
//  ah   @ 41943040  : [4096][1024] f16 = 8 MB

// Single fused cast: outputs are contiguous in ws (xh | wqh | woh).
__global__ void cast_all(const float* __restrict__ x, const float* __restrict__ wqv,
                         const float* __restrict__ wo, f16* __restrict__ out) {
    int i = blockIdx.x * blockDim.x + threadIdx.x;  // 0..2097151 float4s
    const float* src; int li;
    if (i < 1048576)      { src = x;   li = i; }
    else if (i < 1835008) { src = wqv; li = i - 1048576; }
    else                  { src = wo;  li = i - 1835008; }
    float4 v = reinterpret_cast<const float4*>(src)[li];
    f16x4 o = {(f16)v.x, (f16)v.y, (f16)v.z, (f16)v.w};
    reinterpret_cast<f16x4*>(out)[i] = o;
}

// ---------------- QKV GEMM: C[4096x3072] = X[4096x1024] * Wqkv^T ----------------
// R7: 3-deep pipelined K-loop. BK=32, 3 LDS buffers (ring t%3): while computing
// tile t, tile t+2 is being staged; tile t+1 is landing. One raw s_barrier per
// tile with counted s_waitcnt vmcnt(4) (never drains the queue in steady state).
__global__ __launch_bounds__(256, 3) void gemm_qkv(
    const f16* __restrict__ A, const f16* __restrict__ B,
    f16* __restrict__ outq, f16* __restrict__ outk, f16* __restrict__ outvt)
{
    __shared__ f16 As[3][128 * 32];
    __shared__ f16 Bs[3][128 * 32];
    const int tid = threadIdx.x;
    const int lane = tid & 63;
    const int wave = tid >> 6;
    const int wm = wave >> 1, wn = wave & 1;
    const int bm = blockIdx.y * 128, bn = blockIdx.x * 128;
    const int fr = lane & 15, fq = lane >> 4;

    const int srow = tid >> 2;                                    // 0..63
    const int su = (tid & 3) ^ (srow & 3) ^ ((srow >> 2) & 3);    // swizzled src 16B-unit
    const int uoff = (fq ^ (fr & 3) ^ ((fr >> 2) & 3)) * 8;       // lane-const read offset

    f32x4 acc[4][4] = {};

    auto stg = [&](int tt, int buf) {
        const int k0 = tt * 32;
        gload_lds16(&A[(bm + srow) * 1024 + k0 + su * 8],      &As[buf][tid * 8]);
        gload_lds16(&A[(bm + 64 + srow) * 1024 + k0 + su * 8], &As[buf][2048 + tid * 8]);
        gload_lds16(&B[(bn + srow) * 1024 + k0 + su * 8],      &Bs[buf][tid * 8]);
        gload_lds16(&B[(bn + 64 + srow) * 1024 + k0 + su * 8], &Bs[buf][2048 + tid * 8]);
    };

    auto step = [&](int t, int buf) {
        const int b2 = (buf + 2 >= 3) ? (buf - 1) : (buf + 2);
        if (t < 30) stg(t + 2, b2);
        f16x8 af[4], bf[4];
#pragma unroll
        for (int mt = 0; mt < 4; ++mt)
            af[mt] = *(const f16x8*)&As[buf][(wm * 64 + mt * 16 + fr) * 32 + uoff];
#pragma unroll
        for (int nt = 0; nt < 4; ++nt)
            bf[nt] = *(const f16x8*)&Bs[buf][(wn * 64 + nt * 16 + fr) * 32 + uoff];
        __builtin_amdgcn_s_setprio(1);
#pragma unroll
        for (int mt = 0; mt < 4; ++mt)
#pragma unroll
            for (int nt = 0; nt < 4; ++nt)
                acc[mt][nt] = MFMA16(af[mt], bf[nt], acc[mt][nt]);
        __builtin_amdgcn_s_setprio(0);
        if (t < 30) { asm volatile("s_waitcnt vmcnt(4)" ::: "memory"); }
        else        { asm volatile("s_waitcnt vmcnt(0)" ::: "memory"); }
        __builtin_amdgcn_s_barrier();
        __builtin_amdgcn_sched_barrier(0);
    };

    stg(0, 0);
    stg(1, 1);
    asm volatile("s_waitcnt vmcnt(4)" ::: "memory");
    __builtin_amdgcn_s_barrier();
    __builtin_amdgcn_sched_barrier(0);
#pragma unroll 1
    for (int tb = 0; tb < 30; tb += 3) {
        step(tb, 0);
        step(tb + 1, 1);
        step(tb + 2, 2);
    }
    step(30, 0);
    step(31, 1);

    const int x = blockIdx.x;
    if (x < 16) {
        // Q (x<8) or K block: uniform target, row-layout [bh][s][64]
        f16* base = (x < 8) ? outq : outk;
        const float scale = (x < 8) ? QSCALE : 1.0f;
        const int coloff = (x < 8) ? bn : (bn - 1024);
#pragma unroll
        for (int mt = 0; mt < 4; ++mt)
#pragma unroll
            for (int nt = 0; nt < 4; ++nt)
#pragma unroll
                for (int i = 0; i < 4; ++i) {
                    int row = bm + wm * 64 + mt * 16 + fq * 4 + i;  // (s*2+b)
                    int col = coloff + wn * 64 + nt * 16 + fr;      // 0..1023
                    int s = row >> 1, b = row & 1;
                    int h = col >> 6, dk = col & 63;
                    base[((b * 16 + h) * 2048 + s) * 64 + dk] = (f16)(acc[mt][nt][i] * scale);
                }
    } else {
        // V block: LDS transpose (2 passes over wn halves) -> vt[bh][dk][s]
        const int xb = x - 16;              // 0..7
        const int s0 = bm >> 1;             // 64-aligned s base
        f16* Ts = &As[0][0];                // [128][76] = 9728 f16 (fits in As[3][4096])
#pragma unroll
        for (int p = 0; p < 2; ++p) {
            __syncthreads();
            if (wn == p) {
#pragma unroll
                for (int mt = 0; mt < 4; ++mt)
#pragma unroll
                    for (int nt = 0; nt < 4; ++nt)
#pragma unroll
                        for (int i = 0; i < 4; ++i) {
                            int row = wm * 64 + mt * 16 + fq * 4 + i;  // 0..127 local
                            int cl = nt * 16 + fr;                     // 0..63 local col
                            Ts[(cl * 2 + (row & 1)) * 76 + (row >> 1)] = (f16)acc[mt][nt][i];
                        }
            }
            __syncthreads();
            const int h = xb * 2 + p;
            const int sj = tid & 7;
#pragma unroll
            for (int it = 0; it < 4; ++it) {
                int idx = (tid >> 3) + it * 32;     // 0..127
                int bsel = idx & 1, dk = idx >> 1;  // b, dk(=cl)
                f16x8 v = *(const f16x8*)&Ts[(dk * 2 + bsel) * 76 + sj * 8];
                *(f16x8*)&outvt[((bsel * 16 + h) * 64 + dk) * 2048 + s0 + sj * 8] = v;
            }
        }
    }
}

// ---------------- Flash attention (causal) — R16: R11 + swapped-QK b64 P-spill ----------
// Base = exact R11 (best: 8 waves, complementary A/B tile split, K+V LDS ring-3,
// counted vmcnt(2), XCD swizzle bh%8==XCD, setprio). R15 (V from L2) regressed 1.8x
// (scatter loads, latency exposed) — reverted.
// NEW: dual-block iterations are LDS-issue-bound (~216 cyc/wave-compute; 96 of
// those are 16 scalar ds_write_b16 P-spills). Swap the QK^T operands (mfma(K,Q),
// numerically verified in R8): lane (fr,fq) then holds P^T[k=ct*16+fq*4+i][q=fr],
// contiguous in k -> P spills as 4x ds_write_b64 (f16x4), and the row-sum is one
// scalar/lane (reduce = 2 shfl_xor + lane-broadcast in epilogue). P-read layout,
// PV, o[] layout, and output indexing all unchanged from R11.
__global__ __launch_bounds__(512) void attn_kernel(
    const f16* __restrict__ qg, const f16* __restrict__ kg,
    const f16* __restrict__ vtg, f16* __restrict__ attn)
{
    __shared__ f16 Ks[3][64 * 64];
    __shared__ f16 Vs[3][64 * 64];
    __shared__ f16 plds[8][16 * 72];
    const int tid = threadIdx.x;
    const int lane = tid & 63;
    const int wave = tid >> 6;      // 0..7

    // XCD-aware remap (bijective on 512): XCD = w&7 == bh&7
    const int w = blockIdx.x + (blockIdx.y << 4);
    const int xcd = w & 7;
    const int idx = w >> 3;                  // 0..63 within XCD, dispatch order
    const int bh = xcd + ((idx & 3) << 3);   // 0..31, bh%8 == xcd
    const int qpair = idx >> 2;              // 0..15, longest stream first

    const int b = bh >> 4, h = bh & 15;
    const int fr = lane & 15, fq = lane >> 4;

    const bool isB = wave < 4;
    const int w4 = wave & 3;
    const int qrow = (isB ? (31 - qpair) : qpair) * 64 + w4 * 16;  // wave's 16-row base
    const int nB = 32 - qpair;              // chunks streamed by the block (>=17)
    const int nK = isB ? nB : (qpair + 1);  // chunks this wave computes

    const f16* Q  = qg  + bh * 2048 * 64;
    const f16* K  = kg  + bh * 2048 * 64;
    const f16* VT = vtg + bh * 64 * 2048;
    f16* P = plds[wave];

    const int sr = tid >> 3;                // 0..63: full 64-row chunk in one issue
    const int scu = (tid & 7) ^ (sr & 7);

    f16x8 aq0 = *(const f16x8*)&Q[(qrow + fr) * 64 + fq * 8];
    f16x8 aq1 = *(const f16x8*)&Q[(qrow + fr) * 64 + 32 + fq * 8];

    f32x4 o[4] = {};
    float lsum = 0.f;

    auto stage = [&](int kc, int buf) {
        const int kb = kc * 64;
        gload_lds16(&K[(kb + sr) * 64 + scu * 8], &Ks[buf][tid * 8]);
        gload_lds16(&VT[sr * 2048 + kb + scu * 8], &Vs[buf][tid * 8]);
    };

    auto compute = [&](int kb, const f16* Ksb, const f16* Vsb, bool domask) {
        f32x4 sc[4] = {};
        // swapped QK^T: sc[ct][i] = S[k=kb+ct*16+fq*4+i][q=qrow+fr] (R8-verified)
        __builtin_amdgcn_s_setprio(1);
#pragma unroll
        for (int ct = 0; ct < 4; ++ct) {
            int r = ct * 16 + fr;
            f16x8 kf0 = *(const f16x8*)&Ksb[r * 64 + ((fq ^ (r & 7)) * 8)];
            f16x8 kf1 = *(const f16x8*)&Ksb[r * 64 + (((4 + fq) ^ (r & 7)) * 8)];
            sc[ct] = MFMA16(kf0, aq0, sc[ct]);
            sc[ct] = MFMA16(kf1, aq1, sc[ct]);
        }
        __builtin_amdgcn_s_setprio(0);
        if (domask) {
#pragma unroll
            for (int ct = 0; ct < 4; ++ct) {
                int kk = kb + ct * 16 + fq * 4;   // k index of element i is kk+i
#pragma unroll
                for (int i = 0; i < 4; ++i)
                    if (kk + i > qrow + fr) sc[ct][i] = -1e30f;
            }
        }
        // exp2 + wide b64 P-spill: P[q=fr][k=ct*16+fq*4 ..+3] (R8-verified layout)
#pragma unroll
        for (int ct = 0; ct < 4; ++ct) {
            float p0 = __builtin_amdgcn_exp2f(sc[ct][0]);
            float p1 = __builtin_amdgcn_exp2f(sc[ct][1]);
            float p2 = __builtin_amdgcn_exp2f(sc[ct][2]);
            float p3 = __builtin_amdgcn_exp2f(sc[ct][3]);
            lsum += (p0 + p1) + (p2 + p3);
            f16x4 pk = {(f16)p0, (f16)p1, (f16)p2, (f16)p3};
            *(f16x4*)&P[fr * 72 + ct * 16 + fq * 4] = pk;
        }
        // PV unchanged: ap = P[q=fr][k], bv = V^T rows from LDS
        f16x8 ap0 = *(const f16x8*)&P[fr * 72 + fq * 8];
        f16x8 ap1 = *(const f16x8*)&P[fr * 72 + 32 + fq * 8];
        __builtin_amdgcn_s_setprio(1);
#pragma unroll
        for (int nt = 0; nt < 4; ++nt) {
            int dk = nt * 16 + fr;
            f16x8 bv0 = *(const f16x8*)&Vsb[dk * 64 + ((fq ^ (dk & 7)) * 8)];
            f16x8 bv1 = *(const f16x8*)&Vsb[dk * 64 + (((4 + fq) ^ (dk & 7)) * 8)];
            o[nt] = MFMA16(ap0, bv0, o[nt]);
            o[nt] = MFMA16(ap1, bv1, o[nt]);
        }
        __builtin_amdgcn_s_setprio(0);
    };

    // prologue: stage 0,1; wait for 0 (1 may stay in flight across the barrier)
    stage(0, 0);
    stage(1, 1);
    asm volatile("s_waitcnt vmcnt(2)" ::: "memory");
    __builtin_amdgcn_s_barrier();
    __builtin_amdgcn_sched_barrier(0);

    int cur = 0;
#pragma unroll 1
    for (int kc = 0; kc < nB; ++kc) {
        if (kc + 2 < nB) {
            int b2 = cur + 2; if (b2 >= 3) b2 -= 3;
            stage(kc + 2, b2);
        }
        if (kc < nK) compute(kc * 64, Ks[cur], Vs[cur], kc * 64 + 63 > qrow);
        if (kc + 2 < nB) { asm volatile("s_waitcnt vmcnt(2)" ::: "memory"); }
        else             { asm volatile("s_waitcnt vmcnt(0)" ::: "memory"); }
        __builtin_amdgcn_s_barrier();
        __builtin_amdgcn_sched_barrier(0);
        if (++cur == 3) cur = 0;
    }

    // epilogue: lsum at lane (fr,fq) = partial row-sum for q=fr over its k-subset;
    // reduce over the fq axis (lanes fr, fr+16, fr+32, fr+48).
    float rs = lsum;
    rs += __shfl_xor(rs, 16);
    rs += __shfl_xor(rs, 32);
    float inv = __builtin_amdgcn_rcpf(rs);
#pragma unroll
    for (int i = 0; i < 4; ++i) {
        float invi = __shfl(inv, fq * 4 + i);   // lane with fr == fq*4+i holds inv(q)
        int srow = qrow + fq * 4 + i;
#pragma unroll
        for (int nt = 0; nt < 4; ++nt)
            attn[(srow * 2 + b) * 1024 + h * 64 + nt * 16 + fr] = (f16)(o[nt][i] * invi);
    }
}

// ---------------- Out GEMM: out[4096x1024] = A[4096x1024] * Wout^T + bias ----------------
// Same 3-deep pipelined structure as gemm_qkv (BK=32, ring of 3, counted vmcnt).
__global__ __launch_bounds__(256) void gemm_out(
    const f16* __restrict__ A, const f16* __restrict__ B,
    const float* __restrict__ bias, float* __restrict__ out)
{
    __shared__ f16 As[3][128 * 32];
    __shared__ f16 Bs[3][64 * 32];
    const int tid = threadIdx.x;
    const int lane = tid & 63;
    const int wave = tid >> 6;
    const int wm = wave >> 1, wn = wave & 1;
    const int bm = blockIdx.y * 128, bn = blockIdx.x * 64;
    const int fr = lane & 15, fq = lane >> 4;

    const int srow = tid >> 2;                                    // 0..63
    const int su = (tid & 3) ^ (srow & 3) ^ ((srow >> 2) & 3);
    const int uoff = (fq ^ (fr & 3) ^ ((fr >> 2) & 3)) * 8;

    f32x4 acc[4][2] = {};

    auto stg = [&](int tt, int buf) {
        const int k0 = tt * 32;
        gload_lds16(&A[(bm + srow) * 1024 + k0 + su * 8],      &As[buf][tid * 8]);
        gload_lds16(&A[(bm + 64 + srow) * 1024 + k0 + su * 8], &As[buf][2048 + tid * 8]);
        gload_lds16(&B[(bn + srow) * 1024 + k0 + su * 8],      &Bs[buf][tid * 8]);
    };

    auto step = [&](int t, int buf) {
        const int b2 = (buf + 2 >= 3) ? (buf - 1) : (buf + 2);
        if (t < 30) stg(t + 2, b2);
        f16x8 af[4], bf[2];
#pragma unroll
        for (int mt = 0; mt < 4; ++mt)
            af[mt] = *(const f16x8*)&As[buf][(wm * 64 + mt * 16 + fr) * 32 + uoff];
#pragma unroll
        for (int nt = 0; nt < 2; ++nt)
            bf[nt] = *(const f16x8*)&Bs[buf][(wn * 32 + nt * 16 + fr) * 32 + uoff];
        __builtin_amdgcn_s_setprio(1);
#pragma unroll
        for (int mt = 0; mt < 4; ++mt)
#pragma unroll
            for (int nt = 0; nt < 2; ++nt)
                acc[mt][nt] = MFMA16(af[mt], bf[nt], acc[mt][nt]);
        __builtin_amdgcn_s_setprio(0);
        if (t < 30) { asm volatile("s_waitcnt vmcnt(3)" ::: "memory"); }
        else        { asm volatile("s_waitcnt vmcnt(0)" ::: "memory"); }
        __builtin_amdgcn_s_barrier();
        __builtin_amdgcn_sched_barrier(0);
    };

    stg(0, 0);
    stg(1, 1);
    asm volatile("s_waitcnt vmcnt(3)" ::: "memory");
    __builtin_amdgcn_s_barrier();
    __builtin_amdgcn_sched_barrier(0);
#pragma unroll 1
    for (int tb = 0; tb < 30; tb += 3) {
        step(tb, 0);
        step(tb + 1, 1);
        step(tb + 2, 2);
    }
    step(30, 0);
    step(31, 1);

#pragma unroll
    for (int mt = 0; mt < 4; ++mt)
#pragma unroll
        for (int nt = 0; nt < 2; ++nt)
#pragma unroll
            for (int i = 0; i < 4; ++i) {
                int row = bm + wm * 64 + mt * 16 + fq * 4 + i;
                int col = bn + wn * 32 + nt * 16 + fr;
                out[row * 1024 + col] = acc[mt][nt][i] + bias[col];
            }
}

extern "C" void kernel_launch(void* const* d_in, const int* in_sizes, int n_in,
                              void* d_out, int out_size, void* d_ws, size_t ws_size,
                              hipStream_t stream)
{
    const float* x     = (const float*)d_in[0];
    const float* w_qkv = (const float*)d_in[1];
    const float* w_out = (const float*)d_in[2];
    const float* b_out = (const float*)d_in[3];
    float* out = (float*)d_out;

    char* ws = (char*)d_ws;
    f16* xh  = (f16*)(ws);
    f16* wqh = (f16*)(ws + 8388608);
    f16* woh = (f16*)(ws + 14680064);
    f16* qh  = (f16*)(ws + 16777216);
    f16* kh  = (f16*)(ws + 25165824);
    f16* vt  = (f16*)(ws + 33554432);
    f16* ah  = (f16*)(ws + 41943040);

    cast_all<<<8192, 256, 0, stream>>>(x, w_qkv, w_out, xh);
    gemm_qkv<<<dim3(24, 32), 256, 0, stream>>>(xh, wqh, qh, kh, vt);
    attn_kernel<<<dim3(16, 32), 512, 0, stream>>>(qh, kh, vt, ah);
    gemm_out<<<dim3(16, 32), 256, 0, stream>>>(ah, woh, b_out, out);
}

// Round 12
// 167.194 us; speedup vs baseline: 1.2489x; 1.0304x over previous
//
#include <hip/hip_runtime.h>
#include <cstdint>

typedef _Float16 f16;
typedef _Float16 f16x4 __attribute__((ext_vector_type(4)));
typedef _Float16 f16x8 __attribute__((ext_vector_type(8)));
typedef float f32x4 __attribute__((ext_vector_type(4)));

#define MFMA16(a, b, c) __builtin_amdgcn_mfma_f32_16x16x32_f16(a, b, c, 0, 0, 0)
#define QSCALE 0.1803368801111243f  /* 0.125 * log2(e): scores land in log2 domain */

// direct global->LDS 16B async copy (m97 pattern)
__device__ __forceinline__ void gload_lds16(const void* g, void* l) {
    __builtin_amdgcn_global_load_lds((__attribute__((address_space(1))) void*)(g),
                                     (__attribute__((address_space(3))) void*)(l),
                                     16, 0, 0);
}

// Problem constants: S=2048, B=2, D=1024, H=16, DK=64
// ws layout (bytes):
//  xh   @ 0         : 4096x1024 f16 = 8 MB       (dead after gemm_qkv)
//  wqh  @ 8388608   : 3072x1024 f16 = 6 MB
//  woh  @ 14680064  : 1024x1024 f16 = 2 MB
//  qh   @ 16777216  : [32][2048][64] f16 = 8 MB  (PRE-SCALED by 0.125*log2e)
//  kh   @ 25165824  : [32][2048][64] f16 = 8 MB
//  vt   @ 33554432  : [32][64][2048] f16 = 8 MB  (V transposed, written by gemm_qkv)
//  ah   @ 41943040  : [4096][1024] f16 = 8 MB

// Single fused cast: outputs are contiguous in ws (xh | wqh | woh).
__global__ void cast_all(const float* __restrict__ x, const float* __restrict__ wqv,
                         const float* __restrict__ wo, f16* __restrict__ out) {
    int i = blockIdx.x * blockDim.x + threadIdx.x;  // 0..2097151 float4s
    const float* src; int li;
    if (i < 1048576)      { src = x;   li = i; }
    else if (i < 1835008) { src = wqv; li = i - 1048576; }
    else                  { src = wo;  li = i - 1835008; }
    float4 v = reinterpret_cast<const float4*>(src)[li];
    f16x4 o = {(f16)v.x, (f16)v.y, (f16)v.z, (f16)v.w};
    reinterpret_cast<f16x4*>(out)[i] = o;
}

// ---------------- QKV GEMM: C[4096x3072] = X[4096x1024] * Wqkv^T ----------------
// R7: 3-deep pipelined K-loop. BK=32, 3 LDS buffers (ring t%3): while computing
// tile t, tile t+2 is being staged; tile t+1 is landing. One raw s_barrier per
// tile with counted s_waitcnt vmcnt(4) (never drains the queue in steady state).
__global__ __launch_bounds__(256, 3) void gemm_qkv(
    const f16* __restrict__ A, const f16* __restrict__ B,
    f16* __restrict__ outq, f16* __restrict__ outk, f16* __restrict__ outvt)
{
    __shared__ f16 As[3][128 * 32];
    __shared__ f16 Bs[3][128 * 32];
    const int tid = threadIdx.x;
    const int lane = tid & 63;
    const int wave = tid >> 6;
    const int wm = wave >> 1, wn = wave & 1;
    const int bm = blockIdx.y * 128, bn = blockIdx.x * 128;
    const int fr = lane & 15, fq = lane >> 4;

    const int srow = tid >> 2;                                    // 0..63
    const int su = (tid & 3) ^ (srow & 3) ^ ((srow >> 2) & 3);    // swizzled src 16B-unit
    const int uoff = (fq ^ (fr & 3) ^ ((fr >> 2) & 3)) * 8;       // lane-const read offset

    f32x4 acc[4][4] = {};

    auto stg = [&](int tt, int buf) {
        const int k0 = tt * 32;
        gload_lds16(&A[(bm + srow) * 1024 + k0 + su * 8],      &As[buf][tid * 8]);
        gload_lds16(&A[(bm + 64 + srow) * 1024 + k0 + su * 8], &As[buf][2048 + tid * 8]);
        gload_lds16(&B[(bn + srow) * 1024 + k0 + su * 8],      &Bs[buf][tid * 8]);
        gload_lds16(&B[(bn + 64 + srow) * 1024 + k0 + su * 8], &Bs[buf][2048 + tid * 8]);
    };

    auto step = [&](int t, int buf) {
        const int b2 = (buf + 2 >= 3) ? (buf - 1) : (buf + 2);
        if (t < 30) stg(t + 2, b2);
        f16x8 af[4], bf[4];
#pragma unroll
        for (int mt = 0; mt < 4; ++mt)
            af[mt] = *(const f16x8*)&As[buf][(wm * 64 + mt * 16 + fr) * 32 + uoff];
#pragma unroll
        for (int nt = 0; nt < 4; ++nt)
            bf[nt] = *(const f16x8*)&Bs[buf][(wn * 64 + nt * 16 + fr) * 32 + uoff];
        __builtin_amdgcn_s_setprio(1);
#pragma unroll
        for (int mt = 0; mt < 4; ++mt)
#pragma unroll
            for (int nt = 0; nt < 4; ++nt)
                acc[mt][nt] = MFMA16(af[mt], bf[nt], acc[mt][nt]);
        __builtin_amdgcn_s_setprio(0);
        if (t < 30) { asm volatile("s_waitcnt vmcnt(4)" ::: "memory"); }
        else        { asm volatile("s_waitcnt vmcnt(0)" ::: "memory"); }
        __builtin_amdgcn_s_barrier();
        __builtin_amdgcn_sched_barrier(0);
    };

    stg(0, 0);
    stg(1, 1);
    asm volatile("s_waitcnt vmcnt(4)" ::: "memory");
    __builtin_amdgcn_s_barrier();
    __builtin_amdgcn_sched_barrier(0);
#pragma unroll 1
    for (int tb = 0; tb < 30; tb += 3) {
        step(tb, 0);
        step(tb + 1, 1);
        step(tb + 2, 2);
    }
    step(30, 0);
    step(31, 1);

    const int x = blockIdx.x;
    if (x < 16) {
        // Q (x<8) or K block: uniform target, row-layout [bh][s][64]
        f16* base = (x < 8) ? outq : outk;
        const float scale = (x < 8) ? QSCALE : 1.0f;
        const int coloff = (x < 8) ? bn : (bn - 1024);
#pragma unroll
        for (int mt = 0; mt < 4; ++mt)
#pragma unroll
            for (int nt = 0; nt < 4; ++nt)
#pragma unroll
                for (int i = 0; i < 4; ++i) {
                    int row = bm + wm * 64 + mt * 16 + fq * 4 + i;  // (s*2+b)
                    int col = coloff + wn * 64 + nt * 16 + fr;      // 0..1023
                    int s = row >> 1, b = row & 1;
                    int h = col >> 6, dk = col & 63;
                    base[((b * 16 + h) * 2048 + s) * 64 + dk] = (f16)(acc[mt][nt][i] * scale);
                }
    } else {
        // V block: LDS transpose (2 passes over wn halves) -> vt[bh][dk][s]
        const int xb = x - 16;              // 0..7
        const int s0 = bm >> 1;             // 64-aligned s base
        f16* Ts = &As[0][0];                // [128][76] = 9728 f16 (fits in As[3][4096])
#pragma unroll
        for (int p = 0; p < 2; ++p) {
            __syncthreads();
            if (wn == p) {
#pragma unroll
                for (int mt = 0; mt < 4; ++mt)
#pragma unroll
                    for (int nt = 0; nt < 4; ++nt)
#pragma unroll
                        for (int i = 0; i < 4; ++i) {
                            int row = wm * 64 + mt * 16 + fq * 4 + i;  // 0..127 local
                            int cl = nt * 16 + fr;                     // 0..63 local col
                            Ts[(cl * 2 + (row & 1)) * 76 + (row >> 1)] = (f16)acc[mt][nt][i];
                        }
            }
            __syncthreads();
            const int h = xb * 2 + p;
            const int sj = tid & 7;
#pragma unroll
            for (int it = 0; it < 4; ++it) {
                int idx = (tid >> 3) + it * 32;     // 0..127
                int bsel = idx & 1, dk = idx >> 1;  // b, dk(=cl)
                f16x8 v = *(const f16x8*)&Ts[(dk * 2 + bsel) * 76 + sj * 8];
                *(f16x8*)&outvt[((bsel * 16 + h) * 64 + dk) * 2048 + s0 + sj * 8] = v;
            }
        }
    }
}

// ---------------- Flash attention (causal) — R17: KVBLK=128 pairs, half the barriers ----
// Evidence chain: R12 (SM-chain placement) neutral, R16 (LDS-write count) neutral,
// R13/R14 (iteration count / co-residency) negative -> per-iteration FIXED overhead
// (barrier sync + drain + issue ramp) x 32 iterations dominates. Fix: process TWO
// 64-chunks per barrier iteration (KVBLK=128), ring-2 ping-pong of chunk PAIRS,
// stage-at-top so ~2x compute covers load latency before the vmcnt(0) drain
// (T3 minimum-2-phase pattern). Barrier count 32 -> ~16.
// LDS: Ks[2][2x4096] + Vs[2][2x4096] = 64KB + plds 16KB = exactly 80KB -> 2 blocks/CU.
// plds pad (+72) replaced by XOR swizzle on unpadded [16][64] rows:
//   elem_off ^= (fr&7)<<3  -> write bank (8ct+2fq)^(4(fr&7)): 2 lanes/bank (free);
//   reads land on the 8-cyc wave floor. Compute body = R16 (swapped-QK, verified).
__global__ __launch_bounds__(512) void attn_kernel(
    const f16* __restrict__ qg, const f16* __restrict__ kg,
    const f16* __restrict__ vtg, f16* __restrict__ attn)
{
    __shared__ f16 Ks[2][2 * 4096];
    __shared__ f16 Vs[2][2 * 4096];
    __shared__ f16 plds[8][16 * 64];
    const int tid = threadIdx.x;
    const int lane = tid & 63;
    const int wave = tid >> 6;      // 0..7

    // XCD-aware remap (bijective on 512): XCD = w&7 == bh&7
    const int w = blockIdx.x + (blockIdx.y << 4);
    const int xcd = w & 7;
    const int idx = w >> 3;                  // 0..63 within XCD, dispatch order
    const int bh = xcd + ((idx & 3) << 3);   // 0..31, bh%8 == xcd
    const int qpair = idx >> 2;              // 0..15, longest stream first

    const int b = bh >> 4, h = bh & 15;
    const int fr = lane & 15, fq = lane >> 4;

    const bool isB = wave < 4;
    const int w4 = wave & 3;
    const int qrow = (isB ? (31 - qpair) : qpair) * 64 + w4 * 16;  // wave's 16-row base
    const int nB = 32 - qpair;              // 64-chunks streamed by the block (>=17)
    const int nK = isB ? nB : (qpair + 1);  // 64-chunks this wave computes

    const f16* Q  = qg  + bh * 2048 * 64;
    const f16* K  = kg  + bh * 2048 * 64;
    const f16* VT = vtg + bh * 64 * 2048;
    f16* P = plds[wave];
    const int pswz = (fr & 7) << 3;         // XOR swizzle for P rows (f16 units)

    const int sr = tid >> 3;                // 0..63: full 64-row chunk in one issue
    const int scu = (tid & 7) ^ (sr & 7);

    f16x8 aq0 = *(const f16x8*)&Q[(qrow + fr) * 64 + fq * 8];
    f16x8 aq1 = *(const f16x8*)&Q[(qrow + fr) * 64 + 32 + fq * 8];

    f32x4 o[4] = {};
    float lsum = 0.f;

    // stage one 64-chunk (kc) into half h of pair-buffer buf
    auto stage64 = [&](int kc, int buf, int hh) {
        const int kb = kc * 64;
        gload_lds16(&K[(kb + sr) * 64 + scu * 8], &Ks[buf][hh * 4096 + tid * 8]);
        gload_lds16(&VT[sr * 2048 + kb + scu * 8], &Vs[buf][hh * 4096 + tid * 8]);
    };

    auto compute = [&](int kb, const f16* Ksb, const f16* Vsb, bool domask) {
        f32x4 sc[4] = {};
        // swapped QK^T: sc[ct][i] = S[k=kb+ct*16+fq*4+i][q=qrow+fr] (R8/R16-verified)
        __builtin_amdgcn_s_setprio(1);
#pragma unroll
        for (int ct = 0; ct < 4; ++ct) {
            int r = ct * 16 + fr;
            f16x8 kf0 = *(const f16x8*)&Ksb[r * 64 + ((fq ^ (r & 7)) * 8)];
            f16x8 kf1 = *(const f16x8*)&Ksb[r * 64 + (((4 + fq) ^ (r & 7)) * 8)];
            sc[ct] = MFMA16(kf0, aq0, sc[ct]);
            sc[ct] = MFMA16(kf1, aq1, sc[ct]);
        }
        __builtin_amdgcn_s_setprio(0);
        if (domask) {
#pragma unroll
            for (int ct = 0; ct < 4; ++ct) {
                int kk = kb + ct * 16 + fq * 4;   // k index of element i is kk+i
#pragma unroll
                for (int i = 0; i < 4; ++i)
                    if (kk + i > qrow + fr) sc[ct][i] = -1e30f;
            }
        }
        // exp2 + b64 P-spill into XOR-swizzled row: logical elem (16ct+4fq) -> ^pswz
#pragma unroll
        for (int ct = 0; ct < 4; ++ct) {
            float p0 = __builtin_amdgcn_exp2f(sc[ct][0]);
            float p1 = __builtin_amdgcn_exp2f(sc[ct][1]);
            float p2 = __builtin_amdgcn_exp2f(sc[ct][2]);
            float p3 = __builtin_amdgcn_exp2f(sc[ct][3]);
            lsum += (p0 + p1) + (p2 + p3);
            f16x4 pk = {(f16)p0, (f16)p1, (f16)p2, (f16)p3};
            *(f16x4*)&P[fr * 64 + ((ct * 16 + fq * 4) ^ pswz)] = pk;
        }
        // PV: ap = P[q=fr][k] (swizzle-consistent 8-elem reads: 8(m^r) stays contiguous)
        f16x8 ap0 = *(const f16x8*)&P[fr * 64 + ((fq * 8) ^ pswz)];
        f16x8 ap1 = *(const f16x8*)&P[fr * 64 + ((32 + fq * 8) ^ pswz)];
        __builtin_amdgcn_s_setprio(1);
#pragma unroll
        for (int nt = 0; nt < 4; ++nt) {
            int dk = nt * 16 + fr;
            f16x8 bv0 = *(const f16x8*)&Vsb[dk * 64 + ((fq ^ (dk & 7)) * 8)];
            f16x8 bv1 = *(const f16x8*)&Vsb[dk * 64 + (((4 + fq) ^ (dk & 7)) * 8)];
            o[nt] = MFMA16(ap0, bv0, o[nt]);
            o[nt] = MFMA16(ap1, bv1, o[nt]);
        }
        __builtin_amdgcn_s_setprio(0);
    };

    // prologue: stage pair 0 (chunks 0,1 — nB>=17 so both exist), drain, barrier
    stage64(0, 0, 0);
    stage64(1, 0, 1);
    asm volatile("s_waitcnt vmcnt(0)" ::: "memory");
    __builtin_amdgcn_s_barrier();
    __builtin_amdgcn_sched_barrier(0);

    const int nP = (nB + 1) >> 1;           // pair count (9..16)
#pragma unroll 1
    for (int ip = 0; ip < nP; ++ip) {
        const int buf = ip & 1;
        if (ip + 1 < nP) {
            // stage next pair into the other buffer (issued BEFORE this pair's
            // computes so ~2 computes of latency cover it before the drain)
            stage64(2 * ip + 2, buf ^ 1, 0);
            if (2 * ip + 3 < nB) stage64(2 * ip + 3, buf ^ 1, 1);
        }
        const int kc0 = 2 * ip, kc1 = 2 * ip + 1;
        if (kc0 < nK) compute(kc0 * 64, &Ks[buf][0],    &Vs[buf][0],    kc0 * 64 + 63 > qrow);
        if (kc1 < nK) compute(kc1 * 64, &Ks[buf][4096], &Vs[buf][4096], kc1 * 64 + 63 > qrow);
        asm volatile("s_waitcnt vmcnt(0)" ::: "memory");
        __builtin_amdgcn_s_barrier();
        __builtin_amdgcn_sched_barrier(0);
    }

    // epilogue: lsum at lane (fr,fq) = partial row-sum for q=fr over its k-subset;
    // reduce over the fq axis (lanes fr, fr+16, fr+32, fr+48).
    float rs = lsum;
    rs += __shfl_xor(rs, 16);
    rs += __shfl_xor(rs, 32);
    float inv = __builtin_amdgcn_rcpf(rs);
#pragma unroll
    for (int i = 0; i < 4; ++i) {
        float invi = __shfl(inv, fq * 4 + i);   // lane with fr == fq*4+i holds inv(q)
        int srow = qrow + fq * 4 + i;
#pragma unroll
        for (int nt = 0; nt < 4; ++nt)
            attn[(srow * 2 + b) * 1024 + h * 64 + nt * 16 + fr] = (f16)(o[nt][i] * invi);
    }
}

// ---------------- Out GEMM: out[4096x1024] = A[4096x1024] * Wout^T + bias ----------------
// Same 3-deep pipelined structure as gemm_qkv (BK=32, ring of 3, counted vmcnt).
__global__ __launch_bounds__(256) void gemm_out(
    const f16* __restrict__ A, const f16* __restrict__ B,
    const float* __restrict__ bias, float* __restrict__ out)
{
    __shared__ f16 As[3][128 * 32];
    __shared__ f16 Bs[3][64 * 32];
    const int tid = threadIdx.x;
    const int lane = tid & 63;
    const int wave = tid >> 6;
    const int wm = wave >> 1, wn = wave & 1;
    const int bm = blockIdx.y * 128, bn = blockIdx.x * 64;
    const int fr = lane & 15, fq = lane >> 4;

    const int srow = tid >> 2;                                    // 0..63
    const int su = (tid & 3) ^ (srow & 3) ^ ((srow >> 2) & 3);
    const int uoff = (fq ^ (fr & 3) ^ ((fr >> 2) & 3)) * 8;

    f32x4 acc[4][2] = {};

    auto stg = [&](int tt, int buf) {
        const int k0 = tt * 32;
        gload_lds16(&A[(bm + srow) * 1024 + k0 + su * 8],      &As[buf][tid * 8]);
        gload_lds16(&A[(bm + 64 + srow) * 1024 + k0 + su * 8], &As[buf][2048 + tid * 8]);
        gload_lds16(&B[(bn + srow) * 1024 + k0 + su * 8],      &Bs[buf][tid * 8]);
    };

    auto step = [&](int t, int buf) {
        const int b2 = (buf + 2 >= 3) ? (buf - 1) : (buf + 2);
        if (t < 30) stg(t + 2, b2);
        f16x8 af[4], bf[2];
#pragma unroll
        for (int mt = 0; mt < 4; ++mt)
            af[mt] = *(const f16x8*)&As[buf][(wm * 64 + mt * 16 + fr) * 32 + uoff];
#pragma unroll
        for (int nt = 0; nt < 2; ++nt)
            bf[nt] = *(const f16x8*)&Bs[buf][(wn * 32 + nt * 16 + fr) * 32 + uoff];
        __builtin_amdgcn_s_setprio(1);
#pragma unroll
        for (int mt = 0; mt < 4; ++mt)
#pragma unroll
            for (int nt = 0; nt < 2; ++nt)
                acc[mt][nt] = MFMA16(af[mt], bf[nt], acc[mt][nt]);
        __builtin_amdgcn_s_setprio(0);
        if (t < 30) { asm volatile("s_waitcnt vmcnt(3)" ::: "memory"); }
        else        { asm volatile("s_waitcnt vmcnt(0)" ::: "memory"); }
        __builtin_amdgcn_s_barrier();
        __builtin_amdgcn_sched_barrier(0);
    };

    stg(0, 0);
    stg(1, 1);
    asm volatile("s_waitcnt vmcnt(3)" ::: "memory");
    __builtin_amdgcn_s_barrier();
    __builtin_amdgcn_sched_barrier(0);
#pragma unroll 1
    for (int tb = 0; tb < 30; tb += 3) {
        step(tb, 0);
        step(tb + 1, 1);
        step(tb + 2, 2);
    }
    step(30, 0);
    step(31, 1);

#pragma unroll
    for (int mt = 0; mt < 4; ++mt)
#pragma unroll
        for (int nt = 0; nt < 2; ++nt)
#pragma unroll
            for (int i = 0; i < 4; ++i) {
                int row = bm + wm * 64 + mt * 16 + fq * 4 + i;
                int col = bn + wn * 32 + nt * 16 + fr;
                out[row * 1024 + col] = acc[mt][nt][i] + bias[col];
            }
}

extern "C" void kernel_launch(void* const* d_in, const int* in_sizes, int n_in,
                              void* d_out, int out_size, void* d_ws, size_t ws_size,
                              hipStream_t stream)
{
    const float* x     = (const float*)d_in[0];
    const float* w_qkv = (const float*)d_in[1];
    const float* w_out = (const float*)d_in[2];
    const float* b_out = (const float*)d_in[3];
    float* out = (float*)d_out;

    char* ws = (char*)d_ws;
    f16* xh  = (f16*)(ws);
    f16* wqh = (f16*)(ws + 8388608);
    f16* woh = (f16*)(ws + 14680064);
    f16* qh  = (f16*)(ws + 16777216);
    f16* kh  = (f16*)(ws + 25165824);
    f16* vt  = (f16*)(ws + 33554432);
    f16* ah  = (f16*)(ws + 41943040);

    cast_all<<<8192, 256, 0, stream>>>(x, w_qkv, w_out, xh);
    gemm_qkv<<<dim3(24, 32), 256, 0, stream>>>(xh, wqh, qh, kh, vt);
    attn_kernel<<<dim3(16, 32), 512, 0, stream>>>(qh, kh, vt, ah);
    gemm_out<<<dim3(16, 32), 256, 0, stream>>>(ah, woh, b_out, out);
}